// Round 13
// baseline (925.242 us; speedup 1.0000x reference)
//
#include <hip/hip_runtime.h>

typedef _Float16 half_t;
typedef _Float16 half2_t __attribute__((ext_vector_type(2)));
union pk_u { unsigned int u; half2_t h; };

#define EMB 64
#define NLAYERS 3
#define SUBC 8             // counter planes (one per XCD class)
#define EBLK 8192          // edges per hist/scatter block (defines edge->s mapping)
#define NBLK 1024          // nodes per scan/finalize block

// ---- register-only inclusive scan within a 64-lane wave ----
__device__ inline int wave_incl_scan(int v) {
    #pragma unroll
    for (int off = 1; off < 64; off <<= 1) {
        int u = __shfl_up(v, off);
        if ((threadIdx.x & 63) >= off) v += u;
    }
    return v;
}

// ---- K1: per-(class,node) histogram; s = blockIdx&7 == (edge>>13)&7 ----
__global__ __launch_bounds__(1024) void hist_kernel(
        const int* __restrict__ col, int* __restrict__ cnt2, int E, int NPAD) {
    int base = blockIdx.x * EBLK;
    int s = blockIdx.x & (SUBC - 1);
    int* plane = cnt2 + s * NPAD;
    #pragma unroll
    for (int k = 0; k < 8; ++k) {
        int idx = base + (k << 10) + threadIdx.x;
        if (idx < E) atomicAdd(&plane[col[idx]], 1);
    }
}

// ---- K2: per-block exclusive scan of padded (x32) per-node totals ----
__global__ __launch_bounds__(1024) void scanA_kernel(
        const int* __restrict__ cnt2, int* __restrict__ lstartG,
        int* __restrict__ bsum, int N, int NPAD) {
    __shared__ int wsum[16];
    int node = blockIdx.x * NBLK + threadIdx.x;
    int pt = 0;
    if (node < N) {
        int deg = 0;
        #pragma unroll
        for (int s = 0; s < SUBC; ++s) deg += cnt2[s * NPAD + node];
        pt = (deg + 31) & ~31;
    }
    int v = wave_incl_scan(pt);
    if ((threadIdx.x & 63) == 63) wsum[threadIdx.x >> 6] = v;
    __syncthreads();
    int wid = threadIdx.x >> 6;
    int base = 0;
    #pragma unroll
    for (int w = 0; w < 15; ++w) base += (w < wid) ? wsum[w] : 0;
    if (node < N) lstartG[node] = base + v - pt;
    if (threadIdx.x == 1023) bsum[blockIdx.x] = base + v;
}

// ---- K3: single-block scan of block sums (<=1024 blocks) ----
__global__ __launch_bounds__(1024) void scanB_kernel(
        const int* __restrict__ bsum, int* __restrict__ bbase,
        int* __restrict__ totalG, int nb) {
    __shared__ int wsum[16];
    int t = threadIdx.x;
    int v0 = (t < nb) ? bsum[t] : 0;
    int v = wave_incl_scan(v0);
    if ((t & 63) == 63) wsum[t >> 6] = v;
    __syncthreads();
    int wid = t >> 6;
    int base = 0;
    #pragma unroll
    for (int w = 0; w < 15; ++w) base += (w < wid) ? wsum[w] : 0;
    if (t < nb) bbase[t] = base + v - v0;
    if (t == 1023) *totalG = base + v;
}

// ---- K4: finalize per node: sd/dis, counts -> absolute sub-cursors in cnt2,
//      sentinel pad-fill, fused s0 = fp16(dis*x), zero rows + global slack ----
__global__ __launch_bounds__(1024) void finalize_kernel(
        int* __restrict__ cnt2, const int* __restrict__ lstartG,
        const int* __restrict__ bbase, const int* __restrict__ totalG,
        int* __restrict__ eg, int2* __restrict__ sd, float* __restrict__ dis,
        const float4* __restrict__ uev, const float4* __restrict__ mev,
        uint2* __restrict__ s0v, uint2* __restrict__ sbz,
        int n_users, int N, int NPAD) {
    __shared__ float sdis[NBLK];
    int c0 = blockIdx.x * NBLK;
    int node = c0 + threadIdx.x;
    int sent = N << 7;               // sentinel: byte offset of zero row

    if (node < N) {
        int c[SUBC];
        int deg = 0;
        #pragma unroll
        for (int s = 0; s < SUBC; ++s) { c[s] = cnt2[s * NPAD + node]; deg += c[s]; }
        int pt = (deg + 31) & ~31;
        int start = bbase[blockIdx.x] + lstartG[node];
        float dn = (deg > 0) ? rsqrtf((float)deg) : 0.0f;
        sd[node] = make_int2(start, pt);
        dis[node] = dn;
        sdis[threadIdx.x] = dn;
        int off = start;
        #pragma unroll
        for (int s = 0; s < SUBC; ++s) { int cc = c[s]; cnt2[s * NPAD + node] = off; off += cc; }
        // pad fill: [start+deg, start+pt)
        for (int k = start + deg; k < start + pt; ++k) eg[k] = sent;
        if (node == N - 1) {
            int tot = *totalG;
            for (int k = 0; k < 64; ++k) eg[tot + k] = sent;   // gather prefetch slack
            for (int q = 0; q < 16; ++q) {                      // zero rows (row N)
                s0v[(long long)N * 16 + q] = make_uint2(0u, 0u);
                sbz[(long long)N * 16 + q] = make_uint2(0u, 0u);
            }
        }
    } else {
        sdis[threadIdx.x] = 0.0f;
    }
    __syncthreads();

    // fused s0 init for this block's nodes: s0 = fp16(dis*x)
    int nc = min(NBLK, N - c0);
    for (int i = threadIdx.x; i < nc * 16; i += NBLK) {
        int loc = i >> 4;
        int nd = c0 + loc;
        int q = i & 15;
        const float4* src = (nd < n_users) ? (uev + (long long)nd * 16)
                                           : (mev + (long long)(nd - n_users) * 16);
        float4 v = src[q];
        float dn = sdis[loc];
        pk_u w0, w1;
        w0.h[0] = (half_t)(v.x * dn); w0.h[1] = (half_t)(v.y * dn);
        w1.h[0] = (half_t)(v.z * dn); w1.h[1] = (half_t)(v.w * dn);
        s0v[(long long)nd * 16 + q] = make_uint2(w0.u, w1.u);
    }
}

// ---- K5: direct scatter; SAME geometry as hist (same edge->s mapping) ----
__global__ __launch_bounds__(1024) void scatter_kernel(
        const int* __restrict__ row, const int* __restrict__ col,
        int* __restrict__ cnt2, int* __restrict__ eg, int E, int NPAD) {
    int base = blockIdx.x * EBLK;
    int s = blockIdx.x & (SUBC - 1);
    int* plane = cnt2 + s * NPAD;
    #pragma unroll
    for (int k = 0; k < 8; ++k) {
        int idx = base + (k << 10) + threadIdx.x;
        if (idx < E) {
            int c = col[idx];
            int r = row[idx];
            int pos = atomicAdd(&plane[c], 1);
            eg[pos] = r << 7;            // src byte-offset (src*128)
        }
    }
}

// ---------------- pull propagate: 8 lanes/row (dwordx4), 8 edge phases --------
// UNCHANGED from round 11 (93 us/layer = fetch-path wall).
// NO u-tables: a_k = s_k/dc exactly; layers 1-2 write ONLY s_k.
// LAYER 3 reads s1[node], s2[node] + x, out = (x + s1/dc + s2/dc + a3)/4.
template <int LAYER>
__global__ __launch_bounds__(256) void gather_kernel(
        const int* __restrict__ eg, const int2* __restrict__ sd,
        const float* __restrict__ dis,
        const uint4* __restrict__ tab, uint2* __restrict__ sOut,
        const uint2* __restrict__ s1v, const uint2* __restrict__ s2v,
        const float4* __restrict__ uev, const float4* __restrict__ mev,
        float4* __restrict__ outv, int n_users, int N) {
    int wave = blockIdx.x * (blockDim.x >> 6) + (threadIdx.x >> 6);
    if (wave >= N) return;
    int l = threadIdx.x & 63;
    int p = l & 7;
    int h = l >> 3;
    unsigned pb = (unsigned)p << 4;          // byte offset of this lane's uint4
    const char* tb = (const char*)tab;

    int2 se = sd[wave];
    int j = se.x;
    int e = se.x + se.y;                     // se.y = padded count (x32)
    pk_u a0, a1, a2, a3;
    a0.u = 0; a1.u = 0; a2.u = 0; a3.u = 0;

    if (j < e) {
        int r0 = eg[j + h];
        int r1 = eg[j + 8 + h];
        int r2 = eg[j + 16 + h];
        int r3 = eg[j + 24 + h];
        for (; j < e; j += 32) {
            int n0 = eg[j + 32 + h];         // prefetch next chunk (slack-safe)
            int n1 = eg[j + 40 + h];
            int n2 = eg[j + 48 + h];
            int n3 = eg[j + 56 + h];
            uint4 v0 = *(const uint4*)(tb + ((unsigned)r0 + pb));
            uint4 v1 = *(const uint4*)(tb + ((unsigned)r1 + pb));
            uint4 v2 = *(const uint4*)(tb + ((unsigned)r2 + pb));
            uint4 v3 = *(const uint4*)(tb + ((unsigned)r3 + pb));
            pk_u t;
            t.u = v0.x; a0.h += t.h; t.u = v0.y; a1.h += t.h;
            t.u = v0.z; a2.h += t.h; t.u = v0.w; a3.h += t.h;
            t.u = v1.x; a0.h += t.h; t.u = v1.y; a1.h += t.h;
            t.u = v1.z; a2.h += t.h; t.u = v1.w; a3.h += t.h;
            t.u = v2.x; a0.h += t.h; t.u = v2.y; a1.h += t.h;
            t.u = v2.z; a2.h += t.h; t.u = v2.w; a3.h += t.h;
            t.u = v3.x; a0.h += t.h; t.u = v3.y; a1.h += t.h;
            t.u = v3.z; a2.h += t.h; t.u = v3.w; a3.h += t.h;
            r0 = n0; r1 = n1; r2 = n2; r3 = n3;
        }
    }

    #pragma unroll
    for (int m = 8; m <= 32; m <<= 1) {
        pk_u t;
        t.u = (unsigned int)__shfl_xor((int)a0.u, m); a0.h += t.h;
        t.u = (unsigned int)__shfl_xor((int)a1.u, m); a1.h += t.h;
        t.u = (unsigned int)__shfl_xor((int)a2.u, m); a2.h += t.h;
        t.u = (unsigned int)__shfl_xor((int)a3.u, m); a3.h += t.h;
    }

    if (h < 2) {                             // 16 lanes handle the 64-dim row
        pk_u x0 = h ? a2 : a0;
        pk_u x1 = h ? a3 : a1;
        float dc = dis[wave];
        float g0 = dc * (float)x0.h[0];
        float g1 = dc * (float)x0.h[1];
        float g2 = dc * (float)x1.h[0];
        float g3 = dc * (float)x1.h[1];
        int q = p * 2 + h;
        long long o16 = (long long)wave * 16 + q;
        if (LAYER < 3) {
            pk_u w0, w1;
            w0.h[0] = (half_t)(dc * g0); w0.h[1] = (half_t)(dc * g1);
            w1.h[0] = (half_t)(dc * g2); w1.h[1] = (half_t)(dc * g3);
            sOut[o16] = make_uint2(w0.u, w1.u);
        } else {
            const float4* src = (wave < n_users) ? (uev + (long long)wave * 16)
                                                 : (mev + (long long)(wave - n_users) * 16);
            float4 xv = src[q];
            float inv = (dc > 0.0f) ? (1.0f / dc) : 0.0f;
            uint2 sa2 = s1v[o16];            // s1[node] = fp16(dc*a1)
            uint2 sb2 = s2v[o16];            // s2[node] = fp16(dc*a2)
            pk_u pa, pb2, pc, pd;
            pa.u = sa2.x; pb2.u = sa2.y; pc.u = sb2.x; pd.u = sb2.y;
            float4 r;
            r.x = (xv.x + ((float)pa.h[0]  + (float)pc.h[0]) * inv + g0) * 0.25f;
            r.y = (xv.y + ((float)pa.h[1]  + (float)pc.h[1]) * inv + g1) * 0.25f;
            r.z = (xv.z + ((float)pb2.h[0] + (float)pd.h[0]) * inv + g2) * 0.25f;
            r.w = (xv.w + ((float)pb2.h[1] + (float)pd.h[1]) * inv + g3) * 0.25f;
            outv[o16] = r;
        }
    }
}

extern "C" void kernel_launch(void* const* d_in, const int* in_sizes, int n_in,
                              void* d_out, int out_size, void* d_ws, size_t ws_size,
                              hipStream_t stream) {
    const int*   edge = (const int*)d_in[0];    // [2, E]: row then col
    const float* ue   = (const float*)d_in[2];
    const float* me   = (const float*)d_in[3];
    float*       out  = (float*)d_out;

    const int E        = in_sizes[0] / 2;
    const int n_users  = in_sizes[2] / EMB;
    const int n_movies = in_sizes[3] / EMB;
    const int N        = n_users + n_movies;
    const int* row = edge;
    const int* col = edge + E;
    const int NPAD = (N + 63) & ~63;            // plane stride (XCD-local lines)
    const int eblocks = (E + EBLK - 1) / EBLK;  // hist/scatter geometry (shared!)
    const int nblocks = (N + NBLK - 1) / NBLK;  // scan/finalize geometry

    // workspace layout
    char* ws = (char*)d_ws;
    auto align_up = [](size_t v) { return (v + 255) & ~(size_t)255; };
    int*    cnt2   = (int*)ws;    ws += align_up((size_t)SUBC * NPAD * sizeof(int));
    int*    lstartG= (int*)ws;    ws += align_up((size_t)N * sizeof(int));
    int*    bsum   = (int*)ws;    ws += align_up((size_t)1024 * sizeof(int));
    int*    bbase  = (int*)ws;    ws += align_up((size_t)1024 * sizeof(int));
    int*    totalG = (int*)ws;    ws += align_up((size_t)64 * sizeof(int));
    int2*   sd     = (int2*)ws;   ws += align_up((size_t)N * sizeof(int2));
    float*  dis    = (float*)ws;  ws += align_up((size_t)N * sizeof(float));
    int*    eg     = (int*)ws;    ws += align_up(((size_t)E + 31ull * N + 256) * sizeof(int));
    half_t* sA     = (half_t*)ws; ws += align_up((size_t)(N + 1) * EMB * sizeof(half_t));
    half_t* sB     = (half_t*)ws; ws += align_up((size_t)(N + 1) * EMB * sizeof(half_t));

    // direct global counting sort -> padded CSR (no intermediate tmp)
    hipMemsetAsync(cnt2, 0, (size_t)SUBC * NPAD * sizeof(int), stream);
    hist_kernel<<<eblocks, 1024, 0, stream>>>(col, cnt2, E, NPAD);
    scanA_kernel<<<nblocks, 1024, 0, stream>>>(cnt2, lstartG, bsum, N, NPAD);
    scanB_kernel<<<1, 1024, 0, stream>>>(bsum, bbase, totalG, nblocks);
    finalize_kernel<<<nblocks, 1024, 0, stream>>>(
        cnt2, lstartG, bbase, totalG, eg, sd, dis,
        (const float4*)ue, (const float4*)me, (uint2*)sA, (uint2*)sB,
        n_users, N, NPAD);
    scatter_kernel<<<eblocks, 1024, 0, stream>>>(row, col, cnt2, eg, E, NPAD);

    // 3 propagation layers (atomic-free pull, packed fp16; s-tables only)
    const int waves_per_block = 4;   // 256 threads
    const int gblocks = (N + waves_per_block - 1) / waves_per_block;
    gather_kernel<1><<<gblocks, 256, 0, stream>>>(
        eg, sd, dis, (const uint4*)sA, (uint2*)sB,
        nullptr, nullptr, nullptr, nullptr, nullptr, n_users, N);
    gather_kernel<2><<<gblocks, 256, 0, stream>>>(
        eg, sd, dis, (const uint4*)sB, (uint2*)sA,
        nullptr, nullptr, nullptr, nullptr, nullptr, n_users, N);
    gather_kernel<3><<<gblocks, 256, 0, stream>>>(
        eg, sd, dis, (const uint4*)sA, nullptr,
        (const uint2*)sB, (const uint2*)sA,
        (const float4*)ue, (const float4*)me, (float4*)out, n_users, N);
}